// Round 9
// baseline (135.230 us; speedup 1.0000x reference)
//
#include <hip/hip_runtime.h>
#include <math.h>

#define B_ 64
#define E_ 256
#define S_ 32
#define H_ 16
#define P_ 512
#define KC_ 46

// workspace float offsets
#define WS_OPART  1949696  // 524288 O_part[32][16][64][16]  (s,h,a,d)

typedef short bf16x8 __attribute__((ext_vector_type(8)));
typedef float f32x4  __attribute__((ext_vector_type(4)));

__device__ __forceinline__ ushort f2bf(float f) {
  unsigned u = __float_as_uint(f);
  u = (u + 0x7FFFu + ((u >> 16) & 1u)) >> 16;   // RNE
  return (ushort)u;
}

__device__ __forceinline__ int pairclass(int la, int lb) {
  if (la == lb) return 0;
  int lo = la < lb ? la : lb, hi = la < lb ? lb : la;
  return 1 + lo*9 - (lo*(lo-1))/2 + (hi - lo - 1);
}

// load 8 consecutive fp32 -> bf16x8 A-fragment slice
__device__ __forceinline__ bf16x8 ld_a8(const float* p) {
  float4 v0 = *(const float4*)p;
  float4 v1 = *(const float4*)(p + 4);
  union { ushort u[8]; bf16x8 v; } r;
  r.u[0]=f2bf(v0.x); r.u[1]=f2bf(v0.y); r.u[2]=f2bf(v0.z); r.u[3]=f2bf(v0.w);
  r.u[4]=f2bf(v1.x); r.u[5]=f2bf(v1.y); r.u[6]=f2bf(v1.z); r.u[7]=f2bf(v1.w);
  return r.v;
}

// ============ K0: fused QKV-MFMA + weighted attention per (s,h) ============
// Operands read DIRECTLY from feat (strided gather + cvt) and in_proj_w
// (contiguous fp32 + cvt) — no staging kernel. MFMA fragment mapping is the
// R6/R7-verified one; softmax/PV identical to R7; cm computed locally (R8).
__global__ __launch_bounds__(256) void k_attn(
    const float* __restrict__ feat, const float* __restrict__ ipw,
    const float* __restrict__ bias, const float* __restrict__ fw,
    const int* __restrict__ labels1, float* __restrict__ ws,
    float* __restrict__ out) {
  __shared__ float qT[16*68], kT[16*68], vs[64*20], sc[64*68], cm[64];
  __shared__ int l1s[64], gsA[64], rjA[64], rsA[64];
  const int s = blockIdx.x >> 4, h = blockIdx.x & 15;
  const int t = threadIdx.x;
  const int w = t >> 6, L = t & 63, lane16 = L & 15, quad = L >> 4;
  const int a = t >> 2, dq = t & 3;
  if (blockIdx.x == 0 && t == 0) out[0] = 0.f;   // init for k_final atomics
  // early label load (latency hidden under MFMA-gen)
  int myl1 = (t < 64) ? labels1[t] : 0;
  // ---- MFMA QKV generation for a-tile w ----
  {
    // A rows: W[row][e], row = region + h*16 + lane16, contiguous in e
    const float* wqp = ipw + (size_t)(      h*16 + lane16)*E_ + quad*8;
    const float* wkp = ipw + (size_t)(256 + h*16 + lane16)*E_ + quad*8;
    const float* wvp = ipw + (size_t)(512 + h*16 + lane16)*E_ + quad*8;
    // B col (row of X): X[b][e] = feat[b*E*S + e*S + s], b = w*16+lane16
    const float* xp = feat + (size_t)(w*16 + lane16)*(E_*S_) + (size_t)(quad*8)*S_ + s;
    f32x4 accQ = {0.f,0.f,0.f,0.f}, accK = {0.f,0.f,0.f,0.f}, accV = {0.f,0.f,0.f,0.f};
#pragma unroll
    for (int k = 0; k < 8; ++k) {
      const float* xk = xp + k*32*S_;
      union { ushort u[8]; bf16x8 v; } bx;
#pragma unroll
      for (int u2 = 0; u2 < 8; ++u2) bx.u[u2] = f2bf(xk[u2*S_]);
      bf16x8 aq = ld_a8(wqp + k*32);
      bf16x8 ak = ld_a8(wkp + k*32);
      bf16x8 av = ld_a8(wvp + k*32);
      accQ = __builtin_amdgcn_mfma_f32_16x16x32_bf16(aq, bx.v, accQ, 0, 0, 0);
      accK = __builtin_amdgcn_mfma_f32_16x16x32_bf16(ak, bx.v, accK, 0, 0, 0);
      accV = __builtin_amdgcn_mfma_f32_16x16x32_bf16(av, bx.v, accV, 0, 0, 0);
    }
    float4 bq  = *(const float4*)(bias +       h*16 + quad*4);
    float4 bk  = *(const float4*)(bias + 256 + h*16 + quad*4);
    float4 bv2 = *(const float4*)(bias + 512 + h*16 + quad*4);
    const float bqa[4] = {bq.x,bq.y,bq.z,bq.w};
    const float bka[4] = {bk.x,bk.y,bk.z,bk.w};
    const float bva[4] = {bv2.x,bv2.y,bv2.z,bv2.w};
    const int ag = w*16 + lane16;
#pragma unroll
    for (int r = 0; r < 4; ++r) {
      int d = quad*4 + r;
      qT[d*68 + ag] = (accQ[r] + bqa[r]) * 0.25f;   // fold 1/sqrt(16)
      kT[d*68 + ag] =  accK[r] + bka[r];
      vs[ag*20 + d] =  accV[r] + bva[r];
    }
  }
  // ---- local cm: group sizes, ranks, rowstarts, truncation, padding ----
  if (t < 64) {
    l1s[t] = myl1;
    int gj = l1s[t];
    int gs_ = 0, rj_ = 0;
#pragma unroll 8
    for (int j2 = 0; j2 < 64; ++j2) {
      int m = (l1s[j2] == gj) ? 1 : 0;
      gs_ += m;
      if (j2 < t) rj_ += m;
    }
    gsA[t] = gs_; rjA[t] = rj_;
    int rs_ = 0;
#pragma unroll 8
    for (int i = 0; i < 64; ++i) if (i < t) rs_ += gsA[i];
    rsA[t] = rs_;
    int cnt = 0;
#pragma unroll 8
    for (int i = 0; i < 64; ++i)
      if (l1s[i] == gj && rsA[i] + rj_ < P_) ++cnt;
    int total = rsA[63] + gsA[63];
    if (t == 0 && total < P_) cnt += P_ - total;   // padding pairs -> j=0
    cm[t] = (float)cnt;
  }
  __syncthreads();
  // ---- scores: 4x4 register outer product -> sc[a][b] ----
  {
    const int ta = t & 15, tb = t >> 4;
    float sa[4][4];
#pragma unroll
    for (int r = 0; r < 4; ++r)
#pragma unroll
      for (int c = 0; c < 4; ++c) sa[r][c] = 0.f;
#pragma unroll
    for (int d = 0; d < 16; ++d) {
      float4 qv = *(float4*)(qT + d*68 + ta*4);
      float4 kv = *(float4*)(kT + d*68 + tb*4);
      float qr[4] = {qv.x,qv.y,qv.z,qv.w};
      float kc[4] = {kv.x,kv.y,kv.z,kv.w};
#pragma unroll
      for (int r = 0; r < 4; ++r)
#pragma unroll
        for (int c = 0; c < 4; ++c) sa[r][c] = fmaf(qr[r], kc[c], sa[r][c]);
    }
#pragma unroll
    for (int r = 0; r < 4; ++r)
      *(float4*)(sc + (ta*4+r)*68 + tb*4) =
          make_float4(sa[r][0], sa[r][1], sa[r][2], sa[r][3]);
  }
  __syncthreads();
  // ---- weighted softmax row a, normalized in-place in sc ----
  {
    float pv[16], cmv[16];
#pragma unroll
    for (int i4 = 0; i4 < 4; ++i4) {
      float4 v = *(float4*)(sc + a*68 + dq*16 + i4*4);
      pv[i4*4+0] = v.x; pv[i4*4+1] = v.y; pv[i4*4+2] = v.z; pv[i4*4+3] = v.w;
    }
#pragma unroll
    for (int i = 0; i < 16; ++i) cmv[i] = cm[dq*16 + i];
    float Mx = -1e30f;
#pragma unroll
    for (int i = 0; i < 16; ++i) if (cmv[i] > 0.f) Mx = fmaxf(Mx, pv[i]);
    Mx = fmaxf(Mx, __shfl_xor(Mx, 1));
    Mx = fmaxf(Mx, __shfl_xor(Mx, 2));
    float z = 0.f;
#pragma unroll
    for (int i = 0; i < 16; ++i) {
      float e = (cmv[i] > 0.f) ? cmv[i]*__expf(pv[i]-Mx) : 0.f;
      pv[i] = e; z += e;
    }
    z += __shfl_xor(z, 1);
    z += __shfl_xor(z, 2);
    float rz = 1.0f / z;
#pragma unroll
    for (int i4 = 0; i4 < 4; ++i4)
      *(float4*)(sc + a*68 + dq*16 + i4*4) =
          make_float4(pv[i4*4+0]*rz, pv[i4*4+1]*rz,
                      pv[i4*4+2]*rz, pv[i4*4+3]*rz);
  }
  __syncthreads();
  // ---- PV: wave g owns rows g*16..g*16+15; lane quad spans d ----
  {
    const int g = t >> 6, l = t & 63;
    const int ar = g*16 + (l >> 2), d4 = (l & 3)*4;
    float o0 = 0.f, o1 = 0.f, o2 = 0.f, o3 = 0.f;
#pragma unroll 4
    for (int b4 = 0; b4 < 64; b4 += 4) {
      float4 p4 = *(float4*)(sc + ar*68 + b4);
      float4 va = *(float4*)(vs + (b4+0)*20 + d4);
      float4 vb = *(float4*)(vs + (b4+1)*20 + d4);
      float4 vc = *(float4*)(vs + (b4+2)*20 + d4);
      float4 vd = *(float4*)(vs + (b4+3)*20 + d4);
      o0 = fmaf(p4.x, va.x, fmaf(p4.y, vb.x, fmaf(p4.z, vc.x, fmaf(p4.w, vd.x, o0))));
      o1 = fmaf(p4.x, va.y, fmaf(p4.y, vb.y, fmaf(p4.z, vc.y, fmaf(p4.w, vd.y, o1))));
      o2 = fmaf(p4.x, va.z, fmaf(p4.y, vb.z, fmaf(p4.z, vc.z, fmaf(p4.w, vd.z, o2))));
      o3 = fmaf(p4.x, va.w, fmaf(p4.y, vb.w, fmaf(p4.z, vc.w, fmaf(p4.w, vd.w, o3))));
    }
    const float fwS = fw[s];
    float* dst = ws + WS_OPART + (size_t)s*(H_*B_*16) + h*(B_*16) + t*4;
    *(float4*)dst = make_float4(fwS*o0, fwS*o1, fwS*o2, fwS*o3);
  }
}

// ============ K1: local pair weights + O reduce + logits + lse + CE ========
// logits = hw @ (Wout @ oh + bout*sfw + fb) + hb   (self-contained, R8-verified)
__global__ __launch_bounds__(256) void k_final(
    const float* __restrict__ ws, const int* __restrict__ labels0,
    const int* __restrict__ labels1, const float* __restrict__ wout,
    const float* __restrict__ bout, const float* __restrict__ fw,
    const float* __restrict__ fbi, const float* __restrict__ hw,
    const float* __restrict__ hb, float* __restrict__ out) {
  const int aa = blockIdx.x, t = threadIdx.x;
  __shared__ float ohs[256], hs[256], lg[64], fws[32];
  __shared__ float cls[48], wsh[48], wk[48], denf;
  __shared__ int l0s[64], l1s[64], gsA[64], rjA[64], rsA[64];
  if (t < 64) { l0s[t] = labels0[t]; l1s[t] = labels1[t]; }
  if (t < 32) fws[t] = fw[t];
  if (t < 48) { cls[t] = 0.f; wk[t] = 0.f; }
  if (t == 0) denf = 0.f;
  __syncthreads();
  if (t < 64) {           // group sizes, in-group ranks, rowstarts
    int gj = l1s[t];
    int gs_ = 0, rj_ = 0;
#pragma unroll 8
    for (int j2 = 0; j2 < 64; ++j2) {
      int m = (l1s[j2] == gj) ? 1 : 0;
      gs_ += m;
      if (j2 < t) rj_ += m;
    }
    gsA[t] = gs_; rjA[t] = rj_;
    int rs_ = 0;
#pragma unroll 8
    for (int i = 0; i < 64; ++i) if (i < t) rs_ += gsA[i];
    rsA[t] = rs_;
  }
  __syncthreads();
  // cls over selected (valid) pairs
  for (int u = 0; u < 16; ++u) {
    int idx = t*16 + u; int i = idx >> 6, j = idx & 63;
    if (l1s[i] == l1s[j] && rsA[i] + rjA[j] < P_)
      atomicAdd(&cls[pairclass(l0s[i], l0s[j])], 1.f);
  }
  __syncthreads();
  if (t < KC_) {
    float cv = cls[t];
    wsh[t] = cv > 0.f ? 1.0f/cv : 0.f;
    if (cv > 0.f) atomicAdd(&denf, 1.0f);
  }
  __syncthreads();
  if (t < 64) {           // Wk[aa][y] over this row's selected pairs
    if (l1s[t] == l1s[aa] && rsA[aa] + rjA[t] < P_) {
      int y = pairclass(l0s[aa], l0s[t]);
      atomicAdd(&wk[y], wsh[y]);
    }
  }
  // ---- reduce O_part over s for row aa ----
  {
    const float* op = ws + WS_OPART + (t>>4)*(B_*16) + aa*16 + (t&15);
    float acc = 0.f;
#pragma unroll
    for (int s = 0; s < S_; ++s) acc += op[(size_t)s*(H_*B_*16)];
    ohs[t] = acc;
  }
  __syncthreads();
  // ---- h = Wout @ oh + bout*sfw + fb ----
  {
    float sfw = 0.f;
#pragma unroll
    for (int s2 = 0; s2 < S_; ++s2) sfw += fws[s2];
    float gacc = 0.f;
    const float4* wr = (const float4*)(wout + (size_t)t*E_);
    const float4* o4 = (const float4*)ohs;
#pragma unroll 8
    for (int j = 0; j < 64; ++j) {
      float4 wv = wr[j], ov = o4[j];
      gacc = fmaf(wv.x, ov.x, gacc); gacc = fmaf(wv.y, ov.y, gacc);
      gacc = fmaf(wv.z, ov.z, gacc); gacc = fmaf(wv.w, ov.w, gacc);
    }
    hs[t] = gacc + bout[t]*sfw + fbi[0];
  }
  __syncthreads();
  // ---- logits[k] = hw[k] . h + hb[k]  (4 lanes per k) ----
  {
    const int k = t >> 2, q = t & 3;
    if (k < KC_) {
      float lv = 0.f;
      const float4* h4 = (const float4*)(hw + (size_t)k*E_ + q*64);
      const float4* s4 = (const float4*)(hs + q*64);
#pragma unroll
      for (int j = 0; j < 16; ++j) {
        float4 m = h4[j], o = s4[j];
        lv = fmaf(m.x, o.x, lv); lv = fmaf(m.y, o.y, lv);
        lv = fmaf(m.z, o.z, lv); lv = fmaf(m.w, o.w, lv);
      }
      lv += __shfl_xor(lv, 1);
      lv += __shfl_xor(lv, 2);
      if (q == 0) lg[k] = lv + hb[k];
    }
  }
  __syncthreads();
  if (t < 64) {
    float x = (t < KC_) ? lg[t] : -1e30f;
    float Mx = x;
#pragma unroll
    for (int off = 1; off < 64; off <<= 1) Mx = fmaxf(Mx, __shfl_xor(Mx, off));
    float z = (t < KC_) ? __expf(x - Mx) : 0.f;
#pragma unroll
    for (int off = 1; off < 64; off <<= 1) z += __shfl_xor(z, off);
    float lse = Mx + __logf(z);
    float term = (t < KC_) ? wk[t] * (lse - x) : 0.f;
#pragma unroll
    for (int off = 1; off < 64; off <<= 1) term += __shfl_xor(term, off);
    if (t == 0) atomicAdd(out, term / denf);
  }
}

extern "C" void kernel_launch(void* const* d_in, const int* in_sizes, int n_in,
                              void* d_out, int out_size, void* d_ws, size_t ws_size,
                              hipStream_t stream) {
  const float* feat    = (const float*)d_in[0];
  const int*   labels0 = (const int*)d_in[1];
  const int*   labels1 = (const int*)d_in[2];
  const float* ipw     = (const float*)d_in[3];
  const float* ipb     = (const float*)d_in[4];
  const float* opw     = (const float*)d_in[5];
  const float* opb     = (const float*)d_in[6];
  const float* fw      = (const float*)d_in[7];
  const float* fbi     = (const float*)d_in[8];
  const float* hw      = (const float*)d_in[9];
  const float* hb      = (const float*)d_in[10];
  float* out = (float*)d_out;
  float* ws  = (float*)d_ws;

  k_attn<<<512, 256, 0, stream>>>(feat, ipw, ipb, fw, labels1, ws, out);
  k_final<<<64, 256, 0, stream>>>(ws, labels0, labels1, opw, opb, fw, fbi,
                                  hw, hb, out);
}

// Round 10
// 108.549 us; speedup vs baseline: 1.2458x; 1.2458x over previous
//
#include <hip/hip_runtime.h>
#include <math.h>

#define B_ 64
#define E_ 256
#define S_ 32
#define H_ 16
#define P_ 512
#define KC_ 46

// workspace float offsets (float4-aligned)
#define WS_CM     0        // 64    key multiplicities
#define WS_WK     256      // 2944  Wk[64][46] per-row class weights
#define WS_INVDEN 3328     // 1
#define WS_C      3392     // 46    logit constant c[k]
#define WS_M      3584     // 11776 M[46][256] = Hw @ Wout
#define WS_WB     16384    // 98304 float-slots: Wb[768][256] bf16
#define WS_XF     114688   // 262144 float-slots: XF[32][64][256] bf16 (s,b,e)
#define WS_OPART  1949696  // 524288 O_part[32][16][64][16]  (s,h,a,d)

typedef short bf16x8 __attribute__((ext_vector_type(8)));
typedef float f32x4  __attribute__((ext_vector_type(4)));

__device__ __forceinline__ ushort f2bf(float f) {
  unsigned u = __float_as_uint(f);
  u = (u + 0x7FFFu + ((u >> 16) & 1u)) >> 16;   // RNE
  return (ushort)u;
}

// ============ K0: prep: Wb convert | XF transpose-convert | pairs | M,c ====
__global__ __launch_bounds__(256) void k_prep(
    const float* __restrict__ feat, const float* __restrict__ w,
    const int* __restrict__ labels0, const int* __restrict__ labels1,
    const float* __restrict__ wout, const float* __restrict__ bout,
    const float* __restrict__ fw, const float* __restrict__ fbi,
    const float* __restrict__ hw, const float* __restrict__ hb,
    float* __restrict__ ws, float* __restrict__ out) {
  __shared__ float sm[8448];
  const int bid = blockIdx.x, t = threadIdx.x;
  if (bid < 24) {
    // ---- convert in_proj_w [768][256] fp32 -> Wb bf16 (straight copy) ----
    const float4* src = (const float4*)w;       // 49152 float4s
    ushort* dstW = (ushort*)(ws + WS_WB);
#pragma unroll
    for (int i = 0; i < 8; ++i) {
      int idx = bid*2048 + i*256 + t;
      float4 v = src[idx];
      ushort4 o;
      o.x = f2bf(v.x); o.y = f2bf(v.y); o.z = f2bf(v.z); o.w = f2bf(v.w);
      *(ushort4*)(dstW + (size_t)idx*4) = o;
    }
  } else if (bid < 88) {
    // ---- transpose-convert feat[b][e][s] -> XF[s][b][e] bf16 ----
    const int b = bid - 24;
    const float4* fb = (const float4*)(feat + (size_t)b*(E_*S_));
#pragma unroll
    for (int i = 0; i < 8; ++i) {
      int idx = i*256 + t; int e = idx >> 3, s4 = (idx & 7)*4;
      float4 v = fb[idx];
      sm[e*33 + s4+0] = v.x; sm[e*33 + s4+1] = v.y;
      sm[e*33 + s4+2] = v.z; sm[e*33 + s4+3] = v.w;
    }
    __syncthreads();
    const int s = t >> 3, eb = (t & 7) * 32;    // lanes span e: coalesced stores
    ushort* dstX = (ushort*)(ws + WS_XF) + (size_t)s*(B_*E_) + (size_t)b*E_ + eb;
#pragma unroll
    for (int g = 0; g < 4; ++g) {
      ushort tmp[8];
#pragma unroll
      for (int u = 0; u < 8; ++u) tmp[u] = f2bf(sm[(eb + g*8 + u)*33 + s]);
      *(uint4*)(dstX + g*8) = *(uint4*)tmp;
    }
  } else if (bid == 88) {
    // ---- pair selection, class ids, Wk, cm, inv_den ----
    float* csh = sm;                  // 64
    float* cls = sm + 64;             // 46
    float* wsh = sm + 112;            // 46
    float* den = sm + 160;            // 1
    float* Wk  = sm + 192;            // 2944
    int* scan = (int*)(sm + 3200);    // 256
    int* l0   = (int*)(sm + 3456);    // 64
    int* l1   = (int*)(sm + 3520);    // 64
    int* seli = (int*)(sm + 3584);    // 512
    int* selj = (int*)(sm + 4096);    // 512
    if (t < 64) { l0[t] = labels0[t]; l1[t] = labels1[t]; csh[t] = 0.f; }
    if (t < KC_) cls[t] = 0.f;
    if (t == 0) den[0] = 0.f;
    for (int i = t; i < 2944; i += 256) Wk[i] = 0.f;
    __syncthreads();
    unsigned bits = 0; int c = 0;
    for (int u = 0; u < 16; ++u) {    // contiguous 16-chunk keeps row-major order
      int idx = t*16 + u;
      if (l1[idx>>6] == l1[idx&63]) { bits |= 1u<<u; ++c; }
    }
    scan[t] = c; __syncthreads();
    for (int off = 1; off < 256; off <<= 1) {
      int v = (t >= off) ? scan[t-off] : 0;
      __syncthreads();
      scan[t] += v;
      __syncthreads();
    }
    const int total = scan[255];
    int rank = scan[t] - c;           // exclusive prefix
    for (int p = t; p < P_; p += 256)
      if (p >= total) { seli[p] = 0; selj[p] = 0; }   // fill_value=0
    for (int u = 0; u < 16; ++u) {
      if (bits & (1u<<u)) {
        if (rank < P_) { int idx = t*16+u; seli[rank] = idx>>6; selj[rank] = idx&63; }
        ++rank;
      }
    }
    __syncthreads();
    int ii[2], yy[2]; float vv[2];
#pragma unroll
    for (int r = 0; r < 2; ++r) {
      int p = t + r*256;
      int i = seli[p], j = selj[p];
      atomicAdd(&csh[j], 1.0f);       // multiplicity incl. padding pairs
      int la = l0[i], lb = l0[j];
      int y;
      if (la == lb) y = 0;
      else {
        int lo = la < lb ? la : lb, hi = la < lb ? lb : la;
        y = 1 + lo*9 - (lo*(lo-1))/2 + (hi-lo-1);
      }
      float v = (p < total) ? 1.f : 0.f;
      if (v > 0.f) atomicAdd(&cls[y], 1.f);
      ii[r] = i; yy[r] = y; vv[r] = v;
    }
    __syncthreads();
    if (t < KC_) {
      float cv = cls[t];
      wsh[t] = cv > 0.f ? 1.0f/cv : 0.f;
      if (cv > 0.f) atomicAdd(den, 1.0f);   // sum(wy) == #present classes
    }
    __syncthreads();
#pragma unroll
    for (int r = 0; r < 2; ++r)
      if (vv[r] > 0.f) atomicAdd(&Wk[ii[r]*KC_ + yy[r]], wsh[yy[r]]);
    __syncthreads();
    if (t < 64) ws[WS_CM + t] = csh[t];
    for (int i = t; i < 2944; i += 256) ws[WS_WK + i] = Wk[i];
    if (t == 0) ws[WS_INVDEN] = 1.0f / den[0];
  } else if (bid < 135) {
    // ---- M[k,:] = hw[k,:] @ Wout  and  c[k] ----
    int k = bid - 89;
    float* hwsh = sm;                 // 256
    float* redA = sm + 256;           // 256
    float* redB = sm + 512;           // 256
    hwsh[t] = hw[k*E_ + t];
    __syncthreads();
    float a0 = 0.f;
#pragma unroll 8
    for (int e = 0; e < E_; ++e) a0 = fmaf(hwsh[e], wout[e*E_ + t], a0);
    ws[WS_M + k*E_ + t] = a0;
    redA[t] = hwsh[t];
    redB[t] = hwsh[t]*bout[t];
    __syncthreads();
    for (int off = 128; off > 0; off >>= 1) {
      if (t < off) { redA[t] += redA[t+off]; redB[t] += redB[t+off]; }
      __syncthreads();
    }
    if (t == 0) {
      float sfw = 0.f;
      for (int s = 0; s < S_; ++s) sfw += fw[s];
      ws[WS_C + k] = fbi[0]*redA[0] + sfw*redB[0] + hb[k];
    }
  } else {
    if (t == 0) out[0] = 0.f;
  }
}

// ============ K1: fused QKV-MFMA + weighted attention per (s,h) ============
// MFMA QKV gen (R6/R7-verified fragment mapping) -> LDS; scores via 4x4
// register tiles; softmax kept in REGISTERS (no normalized-P writeback);
// PV as quad-partial sums + butterfly reduce; 2 barriers total.
__global__ __launch_bounds__(256) void k_attn(
    const float* __restrict__ bias, const float* __restrict__ fw,
    float* __restrict__ ws) {
  __shared__ float qT[16*68], kT[16*68], vs[64*20], sc[64*68], cm[64];
  const int s = blockIdx.x >> 4, h = blockIdx.x & 15;
  const int t = threadIdx.x;
  const int w = t >> 6, L = t & 63, lane16 = L & 15, quad = L >> 4;
  const int a = t >> 2, dq = t & 3;
  // ---- MFMA QKV generation for a-tile w ----
  {
    const short* WB = (const short*)(ws + WS_WB);
    const short* XF = (const short*)(ws + WS_XF);
    const short* brow  = XF + (size_t)s*(B_*E_) + (size_t)(w*16 + lane16)*E_ + quad*8;
    const short* arowQ = WB + (size_t)(      h*16 + lane16)*E_ + quad*8;
    const short* arowK = WB + (size_t)(256 + h*16 + lane16)*E_ + quad*8;
    const short* arowV = WB + (size_t)(512 + h*16 + lane16)*E_ + quad*8;
    f32x4 accQ = {0.f,0.f,0.f,0.f}, accK = {0.f,0.f,0.f,0.f}, accV = {0.f,0.f,0.f,0.f};
#pragma unroll
    for (int k = 0; k < 8; ++k) {
      bf16x8 bv = *(const bf16x8*)(brow  + k*32);
      bf16x8 aq = *(const bf16x8*)(arowQ + k*32);
      bf16x8 ak = *(const bf16x8*)(arowK + k*32);
      bf16x8 av = *(const bf16x8*)(arowV + k*32);
      accQ = __builtin_amdgcn_mfma_f32_16x16x32_bf16(aq, bv, accQ, 0, 0, 0);
      accK = __builtin_amdgcn_mfma_f32_16x16x32_bf16(ak, bv, accK, 0, 0, 0);
      accV = __builtin_amdgcn_mfma_f32_16x16x32_bf16(av, bv, accV, 0, 0, 0);
    }
    float4 bq  = *(const float4*)(bias +       h*16 + quad*4);
    float4 bk  = *(const float4*)(bias + 256 + h*16 + quad*4);
    float4 bv2 = *(const float4*)(bias + 512 + h*16 + quad*4);
    const float bqa[4] = {bq.x,bq.y,bq.z,bq.w};
    const float bka[4] = {bk.x,bk.y,bk.z,bk.w};
    const float bva[4] = {bv2.x,bv2.y,bv2.z,bv2.w};
    const int ag = w*16 + lane16;
#pragma unroll
    for (int r = 0; r < 4; ++r) {
      int d = quad*4 + r;
      qT[d*68 + ag] = (accQ[r] + bqa[r]) * 0.25f;   // fold 1/sqrt(16)
      kT[d*68 + ag] =  accK[r] + bka[r];
      vs[ag*20 + d] =  accV[r] + bva[r];
    }
  }
  if (t < 64) cm[t] = ws[WS_CM + t];
  __syncthreads();
  // ---- scores: 4x4 register outer product -> sc[a][b] (raw) ----
  {
    const int ta = t & 15, tb = t >> 4;
    float sa[4][4];
#pragma unroll
    for (int r = 0; r < 4; ++r)
#pragma unroll
      for (int c = 0; c < 4; ++c) sa[r][c] = 0.f;
#pragma unroll
    for (int d = 0; d < 16; ++d) {
      float4 qv = *(float4*)(qT + d*68 + ta*4);
      float4 kv = *(float4*)(kT + d*68 + tb*4);
      float qr[4] = {qv.x,qv.y,qv.z,qv.w};
      float kc[4] = {kv.x,kv.y,kv.z,kv.w};
#pragma unroll
      for (int r = 0; r < 4; ++r)
#pragma unroll
        for (int c = 0; c < 4; ++c) sa[r][c] = fmaf(qr[r], kc[c], sa[r][c]);
    }
#pragma unroll
    for (int r = 0; r < 4; ++r)
      *(float4*)(sc + (ta*4+r)*68 + tb*4) =
          make_float4(sa[r][0], sa[r][1], sa[r][2], sa[r][3]);
  }
  __syncthreads();
  // ---- softmax in regs + PV quad-partials + butterfly reduce + store ----
  {
    float pv[16], cmv[16];
#pragma unroll
    for (int i4 = 0; i4 < 4; ++i4) {
      float4 v = *(float4*)(sc + a*68 + dq*16 + i4*4);
      pv[i4*4+0] = v.x; pv[i4*4+1] = v.y; pv[i4*4+2] = v.z; pv[i4*4+3] = v.w;
    }
#pragma unroll
    for (int i = 0; i < 16; ++i) cmv[i] = cm[dq*16 + i];
    float Mx = -1e30f;
#pragma unroll
    for (int i = 0; i < 16; ++i) if (cmv[i] > 0.f) Mx = fmaxf(Mx, pv[i]);
    Mx = fmaxf(Mx, __shfl_xor(Mx, 1));
    Mx = fmaxf(Mx, __shfl_xor(Mx, 2));
    float z = 0.f;
#pragma unroll
    for (int i = 0; i < 16; ++i) {
      float e = (cmv[i] > 0.f) ? cmv[i]*__expf(pv[i]-Mx) : 0.f;
      pv[i] = e; z += e;
    }
    z += __shfl_xor(z, 1);
    z += __shfl_xor(z, 2);
    // PV partials over this thread's 16 b's (P stays in registers)
    float o[16];
#pragma unroll
    for (int d = 0; d < 16; ++d) o[d] = 0.f;
#pragma unroll
    for (int i = 0; i < 16; ++i) {
      const int b = dq*16 + i;
      const float e = pv[i];
      float4 v0 = *(float4*)(vs + b*20 + 0);
      float4 v1 = *(float4*)(vs + b*20 + 4);
      float4 v2 = *(float4*)(vs + b*20 + 8);
      float4 v3 = *(float4*)(vs + b*20 + 12);
      o[0]  = fmaf(e, v0.x, o[0]);  o[1]  = fmaf(e, v0.y, o[1]);
      o[2]  = fmaf(e, v0.z, o[2]);  o[3]  = fmaf(e, v0.w, o[3]);
      o[4]  = fmaf(e, v1.x, o[4]);  o[5]  = fmaf(e, v1.y, o[5]);
      o[6]  = fmaf(e, v1.z, o[6]);  o[7]  = fmaf(e, v1.w, o[7]);
      o[8]  = fmaf(e, v2.x, o[8]);  o[9]  = fmaf(e, v2.y, o[9]);
      o[10] = fmaf(e, v2.z, o[10]); o[11] = fmaf(e, v2.w, o[11]);
      o[12] = fmaf(e, v3.x, o[12]); o[13] = fmaf(e, v3.y, o[13]);
      o[14] = fmaf(e, v3.z, o[14]); o[15] = fmaf(e, v3.w, o[15]);
    }
    // butterfly across the quad (lanes dq=0..3 share row a)
#pragma unroll
    for (int d = 0; d < 16; ++d) {
      o[d] += __shfl_xor(o[d], 1);
      o[d] += __shfl_xor(o[d], 2);
    }
    const float scale = fw[s] / z;
    // each quad lane stores its d-slice: same dst formula as R7 (t*4 = a*16+dq*4)
    float* dst = ws + WS_OPART + (size_t)s*(H_*B_*16) + h*(B_*16) + t*4;
    *(float4*)dst = make_float4(o[dq*4+0]*scale, o[dq*4+1]*scale,
                                o[dq*4+2]*scale, o[dq*4+3]*scale);
  }
}

// ============ K2: reduce O_part + logits + lse + weighted-CE per row =======
__global__ __launch_bounds__(256) void k_final(
    const float* __restrict__ ws, float* __restrict__ out) {
  const int aa = blockIdx.x, t = threadIdx.x;
  __shared__ float oh[256], lg[64];
  {
    const float* op = ws + WS_OPART + (t>>4)*(B_*16) + aa*16 + (t&15);
    float acc = 0.f;
#pragma unroll
    for (int s = 0; s < S_; ++s) acc += op[(size_t)s*(H_*B_*16)];
    oh[t] = acc;
  }
  __syncthreads();
  const int k = t >> 2, q = t & 3;
  if (k < KC_) {
    float lv = 0.f;
    const float4* M4 = (const float4*)(ws + WS_M + k*E_ + q*64);
    const float4* o4 = (const float4*)(oh + q*64);
#pragma unroll
    for (int j = 0; j < 16; ++j) {
      float4 m = M4[j], o = o4[j];
      lv = fmaf(m.x, o.x, lv); lv = fmaf(m.y, o.y, lv);
      lv = fmaf(m.z, o.z, lv); lv = fmaf(m.w, o.w, lv);
    }
    lv += __shfl_xor(lv, 1);
    lv += __shfl_xor(lv, 2);
    if (q == 0) lg[k] = lv + ws[WS_C + k];
  }
  __syncthreads();
  if (t < 64) {
    float x = (t < KC_) ? lg[t] : -1e30f;
    float Mx = x;
#pragma unroll
    for (int off = 1; off < 64; off <<= 1) Mx = fmaxf(Mx, __shfl_xor(Mx, off));
    float z = (t < KC_) ? __expf(x - Mx) : 0.f;
#pragma unroll
    for (int off = 1; off < 64; off <<= 1) z += __shfl_xor(z, off);
    float lse = Mx + __logf(z);
    float term = (t < KC_) ? ws[WS_WK + aa*KC_ + t] * (lse - x) : 0.f;
#pragma unroll
    for (int off = 1; off < 64; off <<= 1) term += __shfl_xor(term, off);
    if (t == 0) atomicAdd(out, term * ws[WS_INVDEN]);
  }
}

extern "C" void kernel_launch(void* const* d_in, const int* in_sizes, int n_in,
                              void* d_out, int out_size, void* d_ws, size_t ws_size,
                              hipStream_t stream) {
  const float* feat    = (const float*)d_in[0];
  const int*   labels0 = (const int*)d_in[1];
  const int*   labels1 = (const int*)d_in[2];
  const float* ipw     = (const float*)d_in[3];
  const float* ipb     = (const float*)d_in[4];
  const float* opw     = (const float*)d_in[5];
  const float* opb     = (const float*)d_in[6];
  const float* fw      = (const float*)d_in[7];
  const float* fbi     = (const float*)d_in[8];
  const float* hw      = (const float*)d_in[9];
  const float* hb      = (const float*)d_in[10];
  float* out = (float*)d_out;
  float* ws  = (float*)d_ws;

  k_prep<<<136, 256, 0, stream>>>(feat, ipw, labels0, labels1, opw, opb, fw,
                                  fbi, hw, hb, ws, out);
  k_attn<<<512, 256, 0, stream>>>(ipb, fw, ws);
  k_final<<<64, 256, 0, stream>>>(ws, out);
}

// Round 11
// 105.517 us; speedup vs baseline: 1.2816x; 1.0287x over previous
//
#include <hip/hip_runtime.h>
#include <math.h>

#define B_ 64
#define E_ 256
#define S_ 32
#define H_ 16
#define P_ 512
#define KC_ 46

// workspace float offsets (float4-aligned)
#define WS_CM     0        // 64    key multiplicities
#define WS_WK     256      // 2944  Wk[64][46] per-row class weights
#define WS_INVDEN 3328     // 1
#define WS_C      3392     // 46    logit constant c[k]
#define WS_M      3584     // 11776 M[46][256] = Hw @ Wout
#define WS_WB     16384    // 98304 float-slots: Wb[768][256] bf16
#define WS_XF     114688   // 262144 float-slots: XF[32][64][256] bf16 (s,b,e)
#define WS_OPART  1949696  // 524288 O_part[32][16][64][16]  (s,h,a,d)

typedef short bf16x8 __attribute__((ext_vector_type(8)));
typedef float f32x4  __attribute__((ext_vector_type(4)));

__device__ __forceinline__ ushort f2bf(float f) {
  unsigned u = __float_as_uint(f);
  u = (u + 0x7FFFu + ((u >> 16) & 1u)) >> 16;   // RNE
  return (ushort)u;
}

// ============ K0: prep: Wb convert | XF transpose-convert | pairs | M,c ====
__global__ __launch_bounds__(256) void k_prep(
    const float* __restrict__ feat, const float* __restrict__ w,
    const int* __restrict__ labels0, const int* __restrict__ labels1,
    const float* __restrict__ wout, const float* __restrict__ bout,
    const float* __restrict__ fw, const float* __restrict__ fbi,
    const float* __restrict__ hw, const float* __restrict__ hb,
    float* __restrict__ ws, float* __restrict__ out) {
  __shared__ float sm[8448];
  const int bid = blockIdx.x, t = threadIdx.x;
  if (bid < 24) {
    // ---- convert in_proj_w [768][256] fp32 -> Wb bf16 (straight copy) ----
    const float4* src = (const float4*)w;       // 49152 float4s
    ushort* dstW = (ushort*)(ws + WS_WB);
#pragma unroll
    for (int i = 0; i < 8; ++i) {
      int idx = bid*2048 + i*256 + t;
      float4 v = src[idx];
      ushort4 o;
      o.x = f2bf(v.x); o.y = f2bf(v.y); o.z = f2bf(v.z); o.w = f2bf(v.w);
      *(ushort4*)(dstW + (size_t)idx*4) = o;
    }
  } else if (bid < 88) {
    // ---- transpose-convert feat[b][e][s] -> XF[s][b][e] bf16 ----
    const int b = bid - 24;
    const float4* fb = (const float4*)(feat + (size_t)b*(E_*S_));
#pragma unroll
    for (int i = 0; i < 8; ++i) {
      int idx = i*256 + t; int e = idx >> 3, s4 = (idx & 7)*4;
      float4 v = fb[idx];
      sm[e*33 + s4+0] = v.x; sm[e*33 + s4+1] = v.y;
      sm[e*33 + s4+2] = v.z; sm[e*33 + s4+3] = v.w;
    }
    __syncthreads();
    const int s = t >> 3, eb = (t & 7) * 32;    // lanes span e: coalesced stores
    ushort* dstX = (ushort*)(ws + WS_XF) + (size_t)s*(B_*E_) + (size_t)b*E_ + eb;
#pragma unroll
    for (int g = 0; g < 4; ++g) {
      ushort tmp[8];
#pragma unroll
      for (int u = 0; u < 8; ++u) tmp[u] = f2bf(sm[(eb + g*8 + u)*33 + s]);
      *(uint4*)(dstX + g*8) = *(uint4*)tmp;
    }
  } else if (bid == 88) {
    // ---- pair selection, class ids, Wk, cm, inv_den ----
    float* csh = sm;                  // 64
    float* cls = sm + 64;             // 46
    float* wsh = sm + 112;            // 46
    float* den = sm + 160;            // 1
    float* Wk  = sm + 192;            // 2944
    int* scan = (int*)(sm + 3200);    // 256
    int* l0   = (int*)(sm + 3456);    // 64
    int* l1   = (int*)(sm + 3520);    // 64
    int* seli = (int*)(sm + 3584);    // 512
    int* selj = (int*)(sm + 4096);    // 512
    if (t < 64) { l0[t] = labels0[t]; l1[t] = labels1[t]; csh[t] = 0.f; }
    if (t < KC_) cls[t] = 0.f;
    if (t == 0) den[0] = 0.f;
    for (int i = t; i < 2944; i += 256) Wk[i] = 0.f;
    __syncthreads();
    unsigned bits = 0; int c = 0;
    for (int u = 0; u < 16; ++u) {    // contiguous 16-chunk keeps row-major order
      int idx = t*16 + u;
      if (l1[idx>>6] == l1[idx&63]) { bits |= 1u<<u; ++c; }
    }
    scan[t] = c; __syncthreads();
    for (int off = 1; off < 256; off <<= 1) {
      int v = (t >= off) ? scan[t-off] : 0;
      __syncthreads();
      scan[t] += v;
      __syncthreads();
    }
    const int total = scan[255];
    int rank = scan[t] - c;           // exclusive prefix
    for (int p = t; p < P_; p += 256)
      if (p >= total) { seli[p] = 0; selj[p] = 0; }   // fill_value=0
    for (int u = 0; u < 16; ++u) {
      if (bits & (1u<<u)) {
        if (rank < P_) { int idx = t*16+u; seli[rank] = idx>>6; selj[rank] = idx&63; }
        ++rank;
      }
    }
    __syncthreads();
    int ii[2], yy[2]; float vv[2];
#pragma unroll
    for (int r = 0; r < 2; ++r) {
      int p = t + r*256;
      int i = seli[p], j = selj[p];
      atomicAdd(&csh[j], 1.0f);       // multiplicity incl. padding pairs
      int la = l0[i], lb = l0[j];
      int y;
      if (la == lb) y = 0;
      else {
        int lo = la < lb ? la : lb, hi = la < lb ? lb : la;
        y = 1 + lo*9 - (lo*(lo-1))/2 + (hi-lo-1);
      }
      float v = (p < total) ? 1.f : 0.f;
      if (v > 0.f) atomicAdd(&cls[y], 1.f);
      ii[r] = i; yy[r] = y; vv[r] = v;
    }
    __syncthreads();
    if (t < KC_) {
      float cv = cls[t];
      wsh[t] = cv > 0.f ? 1.0f/cv : 0.f;
      if (cv > 0.f) atomicAdd(den, 1.0f);   // sum(wy) == #present classes
    }
    __syncthreads();
#pragma unroll
    for (int r = 0; r < 2; ++r)
      if (vv[r] > 0.f) atomicAdd(&Wk[ii[r]*KC_ + yy[r]], wsh[yy[r]]);
    __syncthreads();
    if (t < 64) ws[WS_CM + t] = csh[t];
    for (int i = t; i < 2944; i += 256) ws[WS_WK + i] = Wk[i];
    if (t == 0) ws[WS_INVDEN] = 1.0f / den[0];
  } else if (bid < 135) {
    // ---- M[k,:] = hw[k,:] @ Wout  and  c[k] ----
    int k = bid - 89;
    float* hwsh = sm;                 // 256
    float* redA = sm + 256;           // 256
    float* redB = sm + 512;           // 256
    hwsh[t] = hw[k*E_ + t];
    __syncthreads();
    float a0 = 0.f;
#pragma unroll 8
    for (int e = 0; e < E_; ++e) a0 = fmaf(hwsh[e], wout[e*E_ + t], a0);
    ws[WS_M + k*E_ + t] = a0;
    redA[t] = hwsh[t];
    redB[t] = hwsh[t]*bout[t];
    __syncthreads();
    for (int off = 128; off > 0; off >>= 1) {
      if (t < off) { redA[t] += redA[t+off]; redB[t] += redB[t+off]; }
      __syncthreads();
    }
    if (t == 0) {
      float sfw = 0.f;
      for (int s = 0; s < S_; ++s) sfw += fw[s];
      ws[WS_C + k] = fbi[0]*redA[0] + sfw*redB[0] + hb[k];
    }
  } else {
    if (t == 0) out[0] = 0.f;
  }
}

// ============ K1: fused QKV-MFMA + weighted attention per (s,h) ============
// Wave w generates Q,K,V 16x16 C-tiles for a-tile w via mfma_16x16x32_bf16,
// stages into LDS, then the verified VALU softmax/PV runs unchanged.
// Bias + 1/sqrt(hd) folded in. (R7 configuration — best measured.)
__global__ __launch_bounds__(256) void k_attn(
    const float* __restrict__ bias, const float* __restrict__ fw,
    float* __restrict__ ws) {
  __shared__ float qT[16*68], kT[16*68], vs[64*20], sc[64*68], cm[64];
  const int s = blockIdx.x >> 4, h = blockIdx.x & 15;
  const int t = threadIdx.x;
  const int w = t >> 6, L = t & 63, lane16 = L & 15, quad = L >> 4;
  const int a = t >> 2, dq = t & 3;
  // ---- MFMA QKV generation for a-tile w ----
  {
    const short* WB = (const short*)(ws + WS_WB);
    const short* XF = (const short*)(ws + WS_XF);
    const short* brow  = XF + (size_t)s*(B_*E_) + (size_t)(w*16 + lane16)*E_ + quad*8;
    const short* arowQ = WB + (size_t)(      h*16 + lane16)*E_ + quad*8;
    const short* arowK = WB + (size_t)(256 + h*16 + lane16)*E_ + quad*8;
    const short* arowV = WB + (size_t)(512 + h*16 + lane16)*E_ + quad*8;
    f32x4 accQ = {0.f,0.f,0.f,0.f}, accK = {0.f,0.f,0.f,0.f}, accV = {0.f,0.f,0.f,0.f};
#pragma unroll
    for (int k = 0; k < 8; ++k) {
      bf16x8 bv = *(const bf16x8*)(brow  + k*32);
      bf16x8 aq = *(const bf16x8*)(arowQ + k*32);
      bf16x8 ak = *(const bf16x8*)(arowK + k*32);
      bf16x8 av = *(const bf16x8*)(arowV + k*32);
      accQ = __builtin_amdgcn_mfma_f32_16x16x32_bf16(aq, bv, accQ, 0, 0, 0);
      accK = __builtin_amdgcn_mfma_f32_16x16x32_bf16(ak, bv, accK, 0, 0, 0);
      accV = __builtin_amdgcn_mfma_f32_16x16x32_bf16(av, bv, accV, 0, 0, 0);
    }
    float4 bq  = *(const float4*)(bias +       h*16 + quad*4);
    float4 bk  = *(const float4*)(bias + 256 + h*16 + quad*4);
    float4 bv2 = *(const float4*)(bias + 512 + h*16 + quad*4);
    const float bqa[4] = {bq.x,bq.y,bq.z,bq.w};
    const float bka[4] = {bk.x,bk.y,bk.z,bk.w};
    const float bva[4] = {bv2.x,bv2.y,bv2.z,bv2.w};
    const int ag = w*16 + lane16;
#pragma unroll
    for (int r = 0; r < 4; ++r) {
      int d = quad*4 + r;
      qT[d*68 + ag] = (accQ[r] + bqa[r]) * 0.25f;   // fold 1/sqrt(16)
      kT[d*68 + ag] =  accK[r] + bka[r];
      vs[ag*20 + d] =  accV[r] + bva[r];
    }
  }
  if (t < 64) cm[t] = ws[WS_CM + t];
  __syncthreads();
  // ---- scores: 4x4 register outer product -> sc[a][b] ----
  {
    const int ta = t & 15, tb = t >> 4;
    float sa[4][4];
#pragma unroll
    for (int r = 0; r < 4; ++r)
#pragma unroll
      for (int c = 0; c < 4; ++c) sa[r][c] = 0.f;
#pragma unroll
    for (int d = 0; d < 16; ++d) {
      float4 qv = *(float4*)(qT + d*68 + ta*4);
      float4 kv = *(float4*)(kT + d*68 + tb*4);
      float qr[4] = {qv.x,qv.y,qv.z,qv.w};
      float kc[4] = {kv.x,kv.y,kv.z,kv.w};
#pragma unroll
      for (int r = 0; r < 4; ++r)
#pragma unroll
        for (int c = 0; c < 4; ++c) sa[r][c] = fmaf(qr[r], kc[c], sa[r][c]);
    }
#pragma unroll
    for (int r = 0; r < 4; ++r)
      *(float4*)(sc + (ta*4+r)*68 + tb*4) =
          make_float4(sa[r][0], sa[r][1], sa[r][2], sa[r][3]);
  }
  __syncthreads();
  // ---- weighted softmax row a, normalized in-place in sc ----
  {
    float pv[16], cmv[16];
#pragma unroll
    for (int i4 = 0; i4 < 4; ++i4) {
      float4 v = *(float4*)(sc + a*68 + dq*16 + i4*4);
      pv[i4*4+0] = v.x; pv[i4*4+1] = v.y; pv[i4*4+2] = v.z; pv[i4*4+3] = v.w;
    }
#pragma unroll
    for (int i = 0; i < 16; ++i) cmv[i] = cm[dq*16 + i];
    float Mx = -1e30f;
#pragma unroll
    for (int i = 0; i < 16; ++i) if (cmv[i] > 0.f) Mx = fmaxf(Mx, pv[i]);
    Mx = fmaxf(Mx, __shfl_xor(Mx, 1));
    Mx = fmaxf(Mx, __shfl_xor(Mx, 2));
    float z = 0.f;
#pragma unroll
    for (int i = 0; i < 16; ++i) {
      float e = (cmv[i] > 0.f) ? cmv[i]*__expf(pv[i]-Mx) : 0.f;
      pv[i] = e; z += e;
    }
    z += __shfl_xor(z, 1);
    z += __shfl_xor(z, 2);
    float rz = 1.0f / z;
#pragma unroll
    for (int i4 = 0; i4 < 4; ++i4)
      *(float4*)(sc + a*68 + dq*16 + i4*4) =
          make_float4(pv[i4*4+0]*rz, pv[i4*4+1]*rz,
                      pv[i4*4+2]*rz, pv[i4*4+3]*rz);
  }
  __syncthreads();
  // ---- PV: wave g owns rows g*16..g*16+15; lane quad spans d ----
  {
    const int g = t >> 6, l = t & 63;
    const int ar = g*16 + (l >> 2), d4 = (l & 3)*4;
    float o0 = 0.f, o1 = 0.f, o2 = 0.f, o3 = 0.f;
#pragma unroll 4
    for (int b4 = 0; b4 < 64; b4 += 4) {
      float4 p4 = *(float4*)(sc + ar*68 + b4);
      float4 va = *(float4*)(vs + (b4+0)*20 + d4);
      float4 vb = *(float4*)(vs + (b4+1)*20 + d4);
      float4 vc = *(float4*)(vs + (b4+2)*20 + d4);
      float4 vd = *(float4*)(vs + (b4+3)*20 + d4);
      o0 = fmaf(p4.x, va.x, fmaf(p4.y, vb.x, fmaf(p4.z, vc.x, fmaf(p4.w, vd.x, o0))));
      o1 = fmaf(p4.x, va.y, fmaf(p4.y, vb.y, fmaf(p4.z, vc.y, fmaf(p4.w, vd.y, o1))));
      o2 = fmaf(p4.x, va.z, fmaf(p4.y, vb.z, fmaf(p4.z, vc.z, fmaf(p4.w, vd.z, o2))));
      o3 = fmaf(p4.x, va.w, fmaf(p4.y, vb.w, fmaf(p4.z, vc.w, fmaf(p4.w, vd.w, o3))));
    }
    const float fwS = fw[s];
    float* dst = ws + WS_OPART + (size_t)s*(H_*B_*16) + h*(B_*16) + t*4;
    *(float4*)dst = make_float4(fwS*o0, fwS*o1, fwS*o2, fwS*o3);
  }
}

// ============ K2: reduce O_part + logits + lse + weighted-CE per row =======
__global__ __launch_bounds__(256) void k_final(
    const float* __restrict__ ws, float* __restrict__ out) {
  const int aa = blockIdx.x, t = threadIdx.x;
  __shared__ float oh[256], lg[64];
  {
    const float* op = ws + WS_OPART + (t>>4)*(B_*16) + aa*16 + (t&15);
    float acc = 0.f;
#pragma unroll
    for (int s = 0; s < S_; ++s) acc += op[(size_t)s*(H_*B_*16)];
    oh[t] = acc;
  }
  __syncthreads();
  const int k = t >> 2, q = t & 3;
  if (k < KC_) {
    float lv = 0.f;
    const float4* M4 = (const float4*)(ws + WS_M + k*E_ + q*64);
    const float4* o4 = (const float4*)(oh + q*64);
#pragma unroll
    for (int j = 0; j < 16; ++j) {
      float4 m = M4[j], o = o4[j];
      lv = fmaf(m.x, o.x, lv); lv = fmaf(m.y, o.y, lv);
      lv = fmaf(m.z, o.z, lv); lv = fmaf(m.w, o.w, lv);
    }
    lv += __shfl_xor(lv, 1);
    lv += __shfl_xor(lv, 2);
    if (q == 0) lg[k] = lv + ws[WS_C + k];
  }
  __syncthreads();
  if (t < 64) {
    float x = (t < KC_) ? lg[t] : -1e30f;
    float Mx = x;
#pragma unroll
    for (int off = 1; off < 64; off <<= 1) Mx = fmaxf(Mx, __shfl_xor(Mx, off));
    float z = (t < KC_) ? __expf(x - Mx) : 0.f;
#pragma unroll
    for (int off = 1; off < 64; off <<= 1) z += __shfl_xor(z, off);
    float lse = Mx + __logf(z);
    float term = (t < KC_) ? ws[WS_WK + aa*KC_ + t] * (lse - x) : 0.f;
#pragma unroll
    for (int off = 1; off < 64; off <<= 1) term += __shfl_xor(term, off);
    if (t == 0) atomicAdd(out, term * ws[WS_INVDEN]);
  }
}

extern "C" void kernel_launch(void* const* d_in, const int* in_sizes, int n_in,
                              void* d_out, int out_size, void* d_ws, size_t ws_size,
                              hipStream_t stream) {
  const float* feat    = (const float*)d_in[0];
  const int*   labels0 = (const int*)d_in[1];
  const int*   labels1 = (const int*)d_in[2];
  const float* ipw     = (const float*)d_in[3];
  const float* ipb     = (const float*)d_in[4];
  const float* opw     = (const float*)d_in[5];
  const float* opb     = (const float*)d_in[6];
  const float* fw      = (const float*)d_in[7];
  const float* fbi     = (const float*)d_in[8];
  const float* hw      = (const float*)d_in[9];
  const float* hb      = (const float*)d_in[10];
  float* out = (float*)d_out;
  float* ws  = (float*)d_ws;

  k_prep<<<136, 256, 0, stream>>>(feat, ipw, labels0, labels1, opw, opb, fw,
                                  fbi, hw, hb, ws, out);
  k_attn<<<512, 256, 0, stream>>>(ipb, fw, ws);
  k_final<<<64, 256, 0, stream>>>(ws, out);
}